// Round 6
// baseline (295.327 us; speedup 1.0000x reference)
//
#include <hip/hip_runtime.h>
#include <hip/hip_bf16.h>

#define E_EDGES 120000
#define NUM_NODES 12000

typedef __attribute__((ext_vector_type(8))) short bfrag;          // 8 bf16
typedef __attribute__((ext_vector_type(8))) unsigned short ushort8;
typedef __attribute__((ext_vector_type(4))) float f32x4;

#define INV_SQRT3 0.57735026918962576f
#define SQRT2_C   1.41421356237309515f
#define N_0E_C    0.14433756729740643f   /* 1/sqrt(48) */
#define NV_C      0.14433756729740643f   /* sqrt(3/48)*1/sqrt(3) = 1/sqrt(48) */
#define WSCALE    0.08838834764831845f   /* 1/sqrt(128) */

__device__ __forceinline__ unsigned short f2bf(float f) {
    union { float f; unsigned int u; } v; v.f = f;
    unsigned int r = v.u + 0x7fffu + ((v.u >> 16) & 1u);
    return (unsigned short)(r >> 16);
}

__device__ __forceinline__ ushort8 pack8(f32x4 a, f32x4 b) {
    ushort8 o;
    o[0] = f2bf(a.x); o[1] = f2bf(a.y); o[2] = f2bf(a.z); o[3] = f2bf(a.w);
    o[4] = f2bf(b.x); o[5] = f2bf(b.y); o[6] = f2bf(b.z); o[7] = f2bf(b.w);
    return o;
}

// ---- Kernel: w_emb (128 x 3072) -> Bt in fragment-consumption order.
// Reads coalesced (consecutive lanes -> consecutive n), writes scattered 2B.
// Layout: tile t, slot c = kb*64 + quad*16 + col, elem j: k=kb*32+quad*8+j, n=t*16+col.
__global__ void k_wt(const float* __restrict__ w_emb, unsigned short* __restrict__ Bt) {
    int i = blockIdx.x * 256 + threadIdx.x;     // i = k*3072 + n
    if (i >= 128 * 3072) return;
    int k = i / 3072;
    int n = i - k * 3072;
    int t = n >> 4, col = n & 15;
    int kb = k >> 5, quad = (k >> 3) & 3, j = k & 7;
    Bt[(size_t)t * 2048 + (size_t)(kb * 64 + quad * 16 + col) * 8 + j] = f2bf(w_emb[i] * WSCALE);
}

// ---- Kernel: per-edge prep: emb bf16 [E][128], rT fp32 tiled [E/32][128][32], cnt
__global__ void k_prep(const float* __restrict__ x, const float* __restrict__ edge_attr,
                       const float* __restrict__ Yij, const int* __restrict__ edge_index,
                       unsigned short* __restrict__ emb, float* __restrict__ rT,
                       float* __restrict__ cnt) {
    int e = blockIdx.x * 256 + threadIdx.x;
    if (e >= E_EDGES) return;
    int dst = edge_index[e];
    int src = edge_index[E_EDGES + e];
    f32x4 y = *(const f32x4*)(Yij + 4 * (long)e);
    float y0 = y.x, y1a = y.y, y1b = y.z, y1c = y.w;
    const float* xd = x + (long)dst * 80;
    const float* xs = x + (long)src * 80;
    const float* ea = edge_attr + (long)e * 64;

    ushort8* embp = (ushort8*)(emb + (long)e * 128);
    float* rb = rT + (long)(e >> 5) * 4096 + (e & 31);   // tiled: group 16KB blocks

    float xsv[80];
#pragma unroll
    for (int i = 0; i < 80; i += 4) {
        f32x4 v = *(const f32x4*)(xs + i);
        xsv[i] = v.x; xsv[i + 1] = v.y; xsv[i + 2] = v.z; xsv[i + 3] = v.w;
    }
#pragma unroll
    for (int cb = 0; cb < 4; ++cb) {
        f32x4 a = *(const f32x4*)(xd + cb * 8);
        f32x4 b = *(const f32x4*)(xd + cb * 8 + 4);
        embp[cb] = pack8(a, b);
    }
#pragma unroll
    for (int cb = 0; cb < 4; ++cb) {
        f32x4 a, b;
        a.x = xsv[cb * 8 + 0]; a.y = xsv[cb * 8 + 1]; a.z = xsv[cb * 8 + 2]; a.w = xsv[cb * 8 + 3];
        b.x = xsv[cb * 8 + 4]; b.y = xsv[cb * 8 + 5]; b.z = xsv[cb * 8 + 6]; b.w = xsv[cb * 8 + 7];
        embp[4 + cb] = pack8(a, b);
    }
#pragma unroll
    for (int cb = 0; cb < 8; ++cb) {
        f32x4 a = *(const f32x4*)(ea + cb * 8);
        f32x4 b = *(const f32x4*)(ea + cb * 8 + 4);
        embp[8 + cb] = pack8(a, b);
    }
#pragma unroll
    for (int u = 0; u < 32; ++u) rb[u * 32] = xsv[u] * y0;
#pragma unroll
    for (int u = 0; u < 16; ++u)
        rb[(32 + u) * 32] =
            (xsv[32 + 3 * u] * y1a + xsv[33 + 3 * u] * y1b + xsv[34 + 3 * u] * y1c) * INV_SQRT3;
#pragma unroll
    for (int u = 0; u < 32; ++u) rb[(48 + u) * 32] = xsv[u];
#pragma unroll
    for (int j = 0; j < 48; ++j) rb[(80 + j) * 32] = xsv[32 + j] * y0;
    atomicAdd(cnt + dst, 1.0f);
}

// ---- Kernel: fused GEMM + u-contraction; Bt via LDS double-buffer DMA.
// Big chunks of 8 tiles (32 KB), 12 barriers per phase-block.
// Phase 0 = {W1,W3} -> out_s; phase 1 = {W2,W4,W5,W6} -> out_g/out_v.
__global__ __launch_bounds__(256, 2) void k_gemm(
    const unsigned short* __restrict__ emb, const unsigned short* __restrict__ Bt,
    const float* __restrict__ rT, const int* __restrict__ edge_index,
    const float* __restrict__ Yij, float* __restrict__ summed) {
    const int lane = threadIdx.x & 63;
    const int wave = threadIdx.x >> 6;
    const int phase = blockIdx.x & 1;
    long e0 = (long)(blockIdx.x >> 1) * 128 + (long)wave * 32;
    const bool dup = (e0 + 32 > E_EDGES);
    if (dup) e0 = E_EDGES - 32;
    const int col = lane & 15, quad = lane >> 4;

    __shared__ __align__(16) char lds[2][32768];   // 64 KB double buffer

    bfrag A[2][4];
#pragma unroll
    for (int s = 0; s < 2; ++s) {
        const unsigned short* ap = emb + (e0 + s * 16 + col) * 128 + quad * 8;
#pragma unroll
        for (int kb = 0; kb < 4; ++kb) A[s][kb] = *(const bfrag*)(ap + kb * 32);
    }

    int wp = 0, rp = 0;
    auto stage = [&](int ci) {   // ci = global big-chunk 0..23 (8 tiles = 32 KB)
        const char* g = (const char*)Bt + (size_t)ci * 32768 + wave * 8192 + lane * 16;
        char* l = &lds[(wp++) & 1][wave * 8192];
#pragma unroll
        for (int j = 0; j < 8; ++j)
            __builtin_amdgcn_global_load_lds(
                (const __attribute__((address_space(1))) unsigned int*)(g + j * 1024),
                (__attribute__((address_space(3))) unsigned int*)(l + j * 1024), 16, 0, 0);
    };
    auto nextbuf = [&](int nxt) -> const char* {
        __syncthreads();
        if (nxt >= 0) stage(nxt);
        return lds[(rp++) & 1];
    };

    f32x4 z = {0.f, 0.f, 0.f, 0.f};
    const float* rbase = rT + ((e0 >> 5) * 4096) + quad * 4;
    auto loadw = [&](int r, f32x4& a, f32x4& b) {
        const float* p = rbase + r * 32;
        a = *(const f32x4*)(p);
        b = *(const f32x4*)(p + 16);
    };

    auto tile = [&](const char* lt, f32x4& c0, f32x4& c1) {
        bfrag B0 = *(const bfrag*)(lt + lane * 16);
        bfrag B1 = *(const bfrag*)(lt + lane * 16 + 1024);
        bfrag B2 = *(const bfrag*)(lt + lane * 16 + 2048);
        bfrag B3 = *(const bfrag*)(lt + lane * 16 + 3072);
        c0 = z; c1 = z;
        c0 = __builtin_amdgcn_mfma_f32_16x16x32_bf16(A[0][0], B0, c0, 0, 0, 0);
        c1 = __builtin_amdgcn_mfma_f32_16x16x32_bf16(A[1][0], B0, c1, 0, 0, 0);
        c0 = __builtin_amdgcn_mfma_f32_16x16x32_bf16(A[0][1], B1, c0, 0, 0, 0);
        c1 = __builtin_amdgcn_mfma_f32_16x16x32_bf16(A[1][1], B1, c1, 0, 0, 0);
        c0 = __builtin_amdgcn_mfma_f32_16x16x32_bf16(A[0][2], B2, c0, 0, 0, 0);
        c1 = __builtin_amdgcn_mfma_f32_16x16x32_bf16(A[1][2], B2, c1, 0, 0, 0);
        c0 = __builtin_amdgcn_mfma_f32_16x16x32_bf16(A[0][3], B3, c0, 0, 0, 0);
        c1 = __builtin_amdgcn_mfma_f32_16x16x32_bf16(A[1][3], B3, c1, 0, 0, 0);
    };

    f32x4 c0, c1;

    if (phase == 0) {
        // W1: BCs 0..7 (rows 4bc..4bc+3), W3: BCs 12..15 (rows 32+4bc..)
        f32x4 acc_s0[2] = {z, z}, acc_s1[2] = {z, z};
        f32x4 ca[4], cb[4], na[4], nb[4];
        stage(0);
#pragma unroll
        for (int i = 0; i < 4; ++i) loadw(i, ca[i], cb[i]);
#pragma unroll 1
        for (int bc = 0; bc < 8; ++bc) {
            const char* buf = nextbuf(bc < 7 ? bc + 1 : 12);
            int nr = (bc < 7) ? 4 * bc + 4 : 32;
#pragma unroll
            for (int i = 0; i < 4; ++i) loadw(nr + i, na[i], nb[i]);
#pragma unroll
            for (int h = 0; h < 2; ++h) {
                const char* hb = buf + h * 16384;
                f32x4 w0a = ca[2 * h], w0b = cb[2 * h];
                f32x4 w1a = ca[2 * h + 1], w1b = cb[2 * h + 1];
                tile(hb,         c0, c1); acc_s0[0] += c0 * w0a; acc_s0[1] += c1 * w0b;
                tile(hb + 4096,  c0, c1); acc_s1[0] += c0 * w0a; acc_s1[1] += c1 * w0b;
                tile(hb + 8192,  c0, c1); acc_s0[0] += c0 * w1a; acc_s0[1] += c1 * w1b;
                tile(hb + 12288, c0, c1); acc_s1[0] += c0 * w1a; acc_s1[1] += c1 * w1b;
            }
#pragma unroll
            for (int i = 0; i < 4; ++i) { ca[i] = na[i]; cb[i] = nb[i]; }
        }
#pragma unroll 1
        for (int bc = 0; bc < 4; ++bc) {
            const char* buf = nextbuf(bc < 3 ? 13 + bc : -1);
            int nr = (bc < 3) ? 36 + 4 * bc : 32;
#pragma unroll
            for (int i = 0; i < 4; ++i) loadw(nr + i, na[i], nb[i]);
#pragma unroll
            for (int h = 0; h < 2; ++h) {
                const char* hb = buf + h * 16384;
                f32x4 w0a = ca[2 * h], w0b = cb[2 * h];
                f32x4 w1a = ca[2 * h + 1], w1b = cb[2 * h + 1];
                tile(hb,         c0, c1); acc_s0[0] += c0 * w0a; acc_s0[1] += c1 * w0b;
                tile(hb + 4096,  c0, c1); acc_s1[0] += c0 * w0a; acc_s1[1] += c1 * w0b;
                tile(hb + 8192,  c0, c1); acc_s0[0] += c0 * w1a; acc_s0[1] += c1 * w1b;
                tile(hb + 12288, c0, c1); acc_s1[0] += c0 * w1a; acc_s1[1] += c1 * w1b;
            }
#pragma unroll
            for (int i = 0; i < 4; ++i) { ca[i] = na[i]; cb[i] = nb[i]; }
        }
        if (dup) return;
#pragma unroll
        for (int s = 0; s < 2; ++s) {
            long eb = e0 + s * 16 + quad * 4;
#pragma unroll
            for (int r = 0; r < 4; ++r) {
                int d = edge_index[eb + r];
                float* base = summed + (long)d * 96;
                atomicAdd(base + col,      N_0E_C * acc_s0[s][r]);
                atomicAdd(base + col + 16, N_0E_C * acc_s1[s][r]);
            }
        }
    } else {
        // W2: BCs 8..11; W4: 16,17; W5: 18..21; W6: 22,23
        f32x4 acc_g[2] = {z, z}, acc_t5[2] = {z, z};
        f32x4 acc_v[2][3] = {{z, z, z}, {z, z, z}};
        stage(8);
        const char* buf = nullptr;
        {   // W2: halves j=0..7, rows 4j..4j+3 -> acc_g
            f32x4 pa[4], pb[4];
#pragma unroll
            for (int i = 0; i < 4; ++i) loadw(i, pa[i], pb[i]);
#pragma unroll 1
            for (int j = 0; j < 8; ++j) {
                if ((j & 1) == 0) { int bc = j >> 1; buf = nextbuf(bc < 3 ? 9 + bc : 16); }
                else buf += 16384;
                f32x4 wa[4], wb[4];
#pragma unroll
                for (int i = 0; i < 4; ++i) { wa[i] = pa[i]; wb[i] = pb[i]; }
                int nr = (j < 7) ? (4 * j + 4) : 32;
#pragma unroll
                for (int i = 0; i < 4; ++i) loadw(nr + i, pa[i], pb[i]);
#pragma unroll
                for (int i = 0; i < 4; ++i) {
                    tile(buf + i * 4096, c0, c1);
                    acc_g[0] += c0 * wa[i]; acc_g[1] += c1 * wb[i];
                }
            }
        }
        {   // W4: halves j=0..3, rows 32+4j+i -> acc_g
            f32x4 pa[4], pb[4];
#pragma unroll
            for (int i = 0; i < 4; ++i) loadw(32 + i, pa[i], pb[i]);
#pragma unroll 1
            for (int j = 0; j < 4; ++j) {
                if ((j & 1) == 0) buf = nextbuf(j == 0 ? 17 : 18);
                else buf += 16384;
                f32x4 wa[4], wb[4];
#pragma unroll
                for (int i = 0; i < 4; ++i) { wa[i] = pa[i]; wb[i] = pb[i]; }
                int nr = (j < 3) ? (36 + 4 * j) : 48;
#pragma unroll
                for (int i = 0; i < 4; ++i) loadw(nr + i, pa[i], pb[i]);
#pragma unroll
                for (int i = 0; i < 4; ++i) {
                    tile(buf + i * 4096, c0, c1);
                    acc_g[0] += c0 * wa[i]; acc_g[1] += c1 * wb[i];
                }
            }
        }
        {   // W5: halves j=0..7, rows 48+4j+i -> acc_t5
            f32x4 pa[4], pb[4];
#pragma unroll
            for (int i = 0; i < 4; ++i) loadw(48 + i, pa[i], pb[i]);
#pragma unroll 1
            for (int j = 0; j < 8; ++j) {
                if ((j & 1) == 0) { int bc = j >> 1; buf = nextbuf(bc < 3 ? 19 + bc : 22); }
                else buf += 16384;
                f32x4 wa[4], wb[4];
#pragma unroll
                for (int i = 0; i < 4; ++i) { wa[i] = pa[i]; wb[i] = pb[i]; }
                int nr = (j < 7) ? (52 + 4 * j) : 48;
#pragma unroll
                for (int i = 0; i < 4; ++i) loadw(nr + i, pa[i], pb[i]);
#pragma unroll
                for (int i = 0; i < 4; ++i) {
                    tile(buf + i * 4096, c0, c1);
                    acc_t5[0] += c0 * wa[i]; acc_t5[1] += c1 * wb[i];
                }
            }
        }
        {   // W6: halves j=0..3, u=4j+i, rows 80+3u+k -> acc_v[k]
            f32x4 va[3], vb[3];
#pragma unroll
            for (int k = 0; k < 3; ++k) loadw(80 + k, va[k], vb[k]);
#pragma unroll 1
            for (int j = 0; j < 4; ++j) {
                if ((j & 1) == 0) buf = nextbuf(j == 0 ? 23 : -1);
                else buf += 16384;
#pragma unroll
                for (int i = 0; i < 4; ++i) {
                    f32x4 wa[3], wb[3];
#pragma unroll
                    for (int k = 0; k < 3; ++k) { wa[k] = va[k]; wb[k] = vb[k]; }
                    int un = 4 * j + i + 1; if (un > 15) un = 0;
#pragma unroll
                    for (int k = 0; k < 3; ++k) loadw(80 + 3 * un + k, va[k], vb[k]);
                    tile(buf + i * 4096, c0, c1);
#pragma unroll
                    for (int k = 0; k < 3; ++k) {
                        acc_v[0][k] += c0 * wa[k];
                        acc_v[1][k] += c1 * wb[k];
                    }
                }
            }
        }
        if (dup) return;
#pragma unroll
        for (int s = 0; s < 2; ++s) {
            long eb = e0 + s * 16 + quad * 4;
#pragma unroll
            for (int r = 0; r < 4; ++r) {
                long e = eb + r;
                int d = edge_index[e];
                float* base = summed + (long)d * 96;
                float y1a = Yij[4 * e + 1], y1b = Yij[4 * e + 2], y1c = Yij[4 * e + 3];
                atomicAdd(base + 32 + col, N_0E_C * acc_g[s][r]);
                float t5 = acc_t5[s][r];
                atomicAdd(base + 48 + col * 3 + 0, NV_C * (t5 * y1a + acc_v[s][0][r]));
                atomicAdd(base + 48 + col * 3 + 1, NV_C * (t5 * y1b + acc_v[s][1][r]));
                atomicAdd(base + 48 + col * 3 + 2, NV_C * (t5 * y1c + acc_v[s][2][r]));
            }
        }
    }
}

// ---- Kernel: mean, relu-gate, residual
__global__ void k_final(const float* __restrict__ x, const float* __restrict__ summed,
                        const float* __restrict__ cnt, float* __restrict__ out) {
    int tid = blockIdx.x * 256 + threadIdx.x;
    if (tid >= NUM_NODES * 80) return;
    int n = tid / 80, c = tid % 80;
    float m = fmaxf(cnt[n], 1.0f);
    float inv = 1.0f / m;
    float val;
    if (c < 32) {
        val = SQRT2_C * fmaxf(summed[(long)n * 96 + c] * inv, 0.0f);
    } else {
        int j = c - 32;
        int w = j / 3;
        float g = SQRT2_C * fmaxf(summed[(long)n * 96 + 32 + w] * inv, 0.0f);
        val = summed[(long)n * 96 + 48 + j] * inv * g;
    }
    out[tid] = x[tid] + val;
}

extern "C" void kernel_launch(void* const* d_in, const int* in_sizes, int n_in,
                              void* d_out, int out_size, void* d_ws, size_t ws_size,
                              hipStream_t stream) {
    const float* x         = (const float*)d_in[0];
    const float* edge_attr = (const float*)d_in[1];
    const float* Yij       = (const float*)d_in[2];
    const int*   edge_index= (const int*)d_in[3];
    const float* w_emb     = (const float*)d_in[4];
    float* out = (float*)d_out;

    char* ws = (char*)d_ws;
    size_t off = 0;
    unsigned short* emb = (unsigned short*)(ws + off); off += (size_t)E_EDGES * 128 * 2;
    unsigned short* Bt  = (unsigned short*)(ws + off); off += (size_t)3072 * 128 * 2;
    off = (off + 255) & ~(size_t)255;
    float* rT     = (float*)(ws + off); off += (size_t)(E_EDGES / 32) * 4096 * 4;
    size_t zoff = off;
    float* summed = (float*)(ws + off); off += (size_t)NUM_NODES * 96 * 4;
    float* cnt    = (float*)(ws + off); off += (size_t)NUM_NODES * 4;

    hipMemsetAsync(ws + zoff, 0, (size_t)NUM_NODES * 97 * 4, stream);
    k_wt  <<<(128 * 3072 + 255) / 256, 256, 0, stream>>>(w_emb, Bt);
    k_prep<<<(E_EDGES + 255) / 256, 256, 0, stream>>>(x, edge_attr, Yij, edge_index, emb, rT, cnt);
    k_gemm<<<2 * ((E_EDGES + 127) / 128), 256, 0, stream>>>(emb, Bt, rT, edge_index, Yij, summed);
    k_final<<<(NUM_NODES * 80 + 255) / 256, 256, 0, stream>>>(x, summed, cnt, out);
}